// Round 3
// baseline (135.398 us; speedup 1.0000x reference)
//
#include <hip/hip_runtime.h>

#define DDIM 1024
#define NEXP 64
#define TOPK 8
#define BK 32
#define ROWS 64
#define NTILE 32
#define TAUF 1.0e-2f
#define TAUB 2.0e-2f

typedef __attribute__((ext_vector_type(8))) short short8;
typedef __attribute__((ext_vector_type(4))) float f32x4;

static __device__ __forceinline__ unsigned int f2u(float f) { return __builtin_bit_cast(unsigned int, f); }
static __device__ __forceinline__ float u2f(unsigned int u) { return __builtin_bit_cast(float, u); }

// f32 -> bf16 round-to-nearest-even (bits)
static __device__ __forceinline__ unsigned short bf_hi_rne(float x) {
    unsigned int u = f2u(x);
    return (unsigned short)((u + (0x7FFFu + ((u >> 16) & 1u))) >> 16);
}

// f32 -> (hi = RNE bf16, lo = trunc bf16 of exact residual)
static __device__ __forceinline__ void split2(float x, unsigned short& h, unsigned short& l) {
    unsigned int u = f2u(x);
    unsigned int uh = (u + (0x7FFFu + ((u >> 16) & 1u))) & 0xFFFF0000u;
    h = (unsigned short)(uh >> 16);
    float rem = x - u2f(uh);
    l = (unsigned short)(f2u(rem) >> 16);
}

// Prologue: build pre-permuted W workspace. For tile t (k=t*32..+32), array a
// (0=wn_hi,1=wn_lo,2=we_hi), expert e, 16B-chunk c: byte offset in ws =
//   t*12288 + a*4096 + ((e*64 + c*16) ^ ((e&7)<<4))
// which is exactly the (swizzled) LDS image; main kernel DMAs it linearly.
__global__ __launch_bounds__(256) void conv_w_kernel(
    const float* __restrict__ Wn, const float* __restrict__ We, char* __restrict__ wsW)
{
    int g = blockIdx.x * 256 + threadIdx.x;   // 0..8191
    int e = g >> 7, c128 = g & 127;
    int k = c128 << 3;                        // 8-float group
    int t = k >> 5, c = (k >> 3) & 3;
    const float* np = Wn + (size_t)e * DDIM + k;
    const float* ep = We + (size_t)e * DDIM + k;
    f32x4 n0 = ((const f32x4*)np)[0], n1 = ((const f32x4*)np)[1];
    f32x4 e0 = ((const f32x4*)ep)[0], e1 = ((const f32x4*)ep)[1];
    short8 nh, nl, eh;
#pragma unroll
    for (int i = 0; i < 4; i++) { unsigned short h, l; split2(n0[i], h, l); nh[i] = (short)h; nl[i] = (short)l; }
#pragma unroll
    for (int i = 0; i < 4; i++) { unsigned short h, l; split2(n1[i], h, l); nh[i + 4] = (short)h; nl[i + 4] = (short)l; }
#pragma unroll
    for (int i = 0; i < 4; i++) eh[i] = (short)bf_hi_rne(e0[i]);
#pragma unroll
    for (int i = 0; i < 4; i++) eh[i + 4] = (short)bf_hi_rne(e1[i]);
    size_t dst = (size_t)t * 12288 + (size_t)((e * 64 + c * 16) ^ ((e & 7) << 4));
    *(short8*)(wsW + dst)        = nh;
    *(short8*)(wsW + dst + 4096) = nl;
    *(short8*)(wsW + dst + 8192) = eh;
}

// LDS map (33792 B -> 4 blocks/CU):
//   xbuf[b]: b*4096, [64 rows][32 k] bf16-hi, swizzled
//   wbuf[b]: 8192 + b*12288, 3 arrays x 4096 (wn_hi, wn_lo, we_hi), swizzled
//   epilogue overlay: s_log[64][65]f32 @0, s_exp @16640, s_gap @33280, s_vb @33536
template <int PRE>
__global__ __launch_bounds__(256, 4) void moe_kernel(
    const float* __restrict__ x, const float* __restrict__ Wn,
    const float* __restrict__ bn, const float* __restrict__ We,
    const char* __restrict__ wsW, float* __restrict__ out)
{
    __shared__ __align__(16) char smem[33792];

    const int tid = threadIdx.x;
    const int wid = tid >> 6;
    const int lane = tid & 63;
    const int fr = lane & 15;
    const int fq = lane >> 4;
    const int blockRow = blockIdx.x * ROWS;

    // staging role: thread covers x row srow, 8-float chunk sg (fully coalesced 128B/row)
    const int srow = tid >> 2, sg = tid & 3;
    const int swz = (srow * 64 + sg * 16) ^ ((srow & 7) << 4);
    const float* xsrc = x + (size_t)(blockRow + srow) * DDIM + sg * 8;

    f32x4 sx0, sx1;                      // x staging regs
    f32x4 sn0, sn1, se0, se1;            // W staging regs (PRE=0 fallback only)

    auto xload = [&](int t) {
        const float* p = xsrc + t * BK;
        sx0 = ((const f32x4*)p)[0];
        sx1 = ((const f32x4*)p)[1];
        if constexpr (!PRE) {
            const float* np = Wn + (size_t)srow * DDIM + t * BK + sg * 8;
            const float* ep = We + (size_t)srow * DDIM + t * BK + sg * 8;
            sn0 = ((const f32x4*)np)[0]; sn1 = ((const f32x4*)np)[1];
            se0 = ((const f32x4*)ep)[0]; se1 = ((const f32x4*)ep)[1];
        }
    };

    auto stage_write = [&](int b) {
        short8 xh;
#pragma unroll
        for (int i = 0; i < 4; i++) xh[i] = (short)bf_hi_rne(sx0[i]);
#pragma unroll
        for (int i = 0; i < 4; i++) xh[i + 4] = (short)bf_hi_rne(sx1[i]);
        *(short8*)(smem + b * 4096 + swz) = xh;
        if constexpr (!PRE) {
            short8 nh, nl, eh;
#pragma unroll
            for (int i = 0; i < 4; i++) { unsigned short h, l; split2(sn0[i], h, l); nh[i] = (short)h; nl[i] = (short)l; }
#pragma unroll
            for (int i = 0; i < 4; i++) { unsigned short h, l; split2(sn1[i], h, l); nh[i + 4] = (short)h; nl[i + 4] = (short)l; }
#pragma unroll
            for (int i = 0; i < 4; i++) eh[i] = (short)bf_hi_rne(se0[i]);
#pragma unroll
            for (int i = 0; i < 4; i++) eh[i + 4] = (short)bf_hi_rne(se1[i]);
            char* wb = smem + 8192 + b * 12288 + swz;
            *(short8*)(wb)        = nh;
            *(short8*)(wb + 4096) = nl;
            *(short8*)(wb + 8192) = eh;
        }
    };

    // W DMA: each wave DMAs exactly the W quarter (16 experts) it will read.
    auto wdma = [&](int t, int b) {
        const char* gs = wsW + (size_t)t * 12288 + wid * 1024 + lane * 16;
        char* ls = smem + 8192 + b * 12288 + wid * 1024;   // wave-uniform base (+lane*16 implicit)
#pragma unroll
        for (int i = 0; i < 3; i++)
            __builtin_amdgcn_global_load_lds(
                (const __attribute__((address_space(1))) void*)(gs + i * 4096),
                (__attribute__((address_space(3))) void*)(ls + i * 4096), 16, 0, 0);
    };

    f32x4 accN[4], accE[4];
#pragma unroll
    for (int rt = 0; rt < 4; rt++) { accN[rt] = f32x4{0.f,0.f,0.f,0.f}; accE[rt] = f32x4{0.f,0.f,0.f,0.f}; }

    const int ecol = wid * 16 + fr;
    const int woffr = (ecol * 64 + fq * 16) ^ ((ecol & 7) << 4);

    auto compute = [&](int b) {
        const char* wb = smem + 8192 + b * 12288;
        short8 wh = *(const short8*)(wb + woffr);
        short8 wl = *(const short8*)(wb + 4096 + woffr);
        short8 eh = *(const short8*)(wb + 8192 + woffr);
#pragma unroll
        for (int rt = 0; rt < 4; rt++) {
            const int row = rt * 16 + fr;
            const int xoff = (row * 64 + fq * 16) ^ ((row & 7) << 4);
            short8 xh = *(const short8*)(smem + b * 4096 + xoff);
            accN[rt] = __builtin_amdgcn_mfma_f32_16x16x32_bf16(xh, wh, accN[rt], 0, 0, 0);
            accN[rt] = __builtin_amdgcn_mfma_f32_16x16x32_bf16(xh, wl, accN[rt], 0, 0, 0);
            accE[rt] = __builtin_amdgcn_mfma_f32_16x16x32_bf16(xh, eh, accE[rt], 0, 0, 0);
        }
    };

    // ---- pipeline: 1 barrier/tile; x loads 2 ahead (regs), W DMA 1 ahead; vmcnt never 0 mid-loop
    xload(0);
    if constexpr (PRE) wdma(0, 0);
    stage_write(0);
    xload(1);
    if constexpr (PRE) asm volatile("s_waitcnt vmcnt(2) lgkmcnt(0)" ::: "memory");
    else               asm volatile("s_waitcnt lgkmcnt(0)" ::: "memory");
    __builtin_amdgcn_s_barrier();
    asm volatile("" ::: "memory");

    for (int t = 0; t < NTILE; ++t) {
        const int cur = t & 1, nxt = cur ^ 1;
        if (t + 1 < NTILE) {
            if constexpr (PRE) wdma(t + 1, nxt);
            stage_write(nxt);                     // waits xload(t+1) regs (compiler vmcnt)
            if (t + 2 < NTILE) xload(t + 2);
        }
        compute(cur);
        if (t + 1 < NTILE) {
            if constexpr (PRE) {
                if (t + 2 < NTILE) asm volatile("s_waitcnt vmcnt(2) lgkmcnt(0)" ::: "memory");
                else               asm volatile("s_waitcnt vmcnt(0) lgkmcnt(0)" ::: "memory");
            } else {
                asm volatile("s_waitcnt lgkmcnt(0)" ::: "memory");
            }
            __builtin_amdgcn_s_barrier();
            asm volatile("" ::: "memory");
        }
    }
    __syncthreads();

    // ---- epilogue overlay
    float* s_log = (float*)smem;                 // [64][65]
    float* s_exp = (float*)(smem + 16640);       // [64][65]
    float* s_gap = (float*)(smem + 33280);       // [64]
    float* s_vb  = (float*)(smem + 33536);       // [64]

    const float be = bn[ecol];
#pragma unroll
    for (int rt = 0; rt < 4; rt++) {
#pragma unroll
        for (int j = 0; j < 4; j++) {
            const int r = rt * 16 + fq * 4 + j;  // C/D: col=lane&15, row=(lane>>4)*4+j
            s_log[r * 65 + ecol] = accN[rt][j] + be;
            s_exp[r * 65 + ecol] = accE[rt][j];
        }
    }
    __syncthreads();

    auto do_row = [&](int r, float& gapo, float& vbo) -> float {
        float selv[TOPK]; int seli[TOPK];
        unsigned long long chosen = 0ull;
#pragma unroll
        for (int t = 0; t < TOPK; t++) {
            float best = -3.0e38f; int bi = 0;
#pragma unroll 4
            for (int e = 0; e < NEXP; e++) {
                float v = s_log[r * 65 + e];
                if (!((chosen >> e) & 1ull) && v > best) { best = v; bi = e; }  // strict > => lowest idx on ties
            }
            selv[t] = best; seli[t] = bi; chosen |= (1ull << bi);
        }
        float v9 = -3.0e38f;
#pragma unroll 4
        for (int e = 0; e < NEXP; e++) {
            float v = s_log[r * 65 + e];
            if (!((chosen >> e) & 1ull) && v > v9) v9 = v;
        }
        gapo = selv[TOPK - 1] - v9;
        vbo = 0.5f * (selv[TOPK - 1] + v9);
        float m = selv[0], Z = 0.f, o = 0.f;
#pragma unroll
        for (int t = 0; t < TOPK; t++) {
            float w = __expf(selv[t] - m);
            Z += w;
            o += w * s_exp[r * 65 + seli[t]];
        }
        return o / Z;
    };

    // selection: wave w owns rows [w*16, w*16+16), one row per lane (lanes 0-15)
    if (lane < 16) {
        const int r = wid * 16 + lane;
        float gap, vb;
        float res = do_row(r, gap, vb);
        out[blockRow + r] = res;
        s_gap[r] = gap; s_vb[r] = vb;
    }
    __syncthreads();

    // fp64 fixup for near-tie rows, distributed: wave w handles rows r%4==w
    for (int r = wid; r < ROWS; r += 4) {
        if (!(s_gap[r] < TAUF)) continue;
        const float vbr = s_vb[r];
        const float ve = s_log[r * 65 + lane];
        unsigned long long cand = __ballot(fabsf(ve - vbr) <= TAUB);
        const f32x4* xq = (const f32x4*)(x + (size_t)(blockRow + r) * DDIM) + lane * 4;
        const f32x4 xv0 = xq[0], xv1 = xq[1], xv2 = xq[2], xv3 = xq[3];
        while (cand) {
            const int ce = __builtin_ctzll(cand);
            cand &= cand - 1;
            const f32x4* wq = (const f32x4*)(Wn + (size_t)ce * DDIM) + lane * 4;
            const f32x4 w0 = wq[0], w1 = wq[1], w2 = wq[2], w3 = wq[3];
            double s = 0.0;
#pragma unroll
            for (int i = 0; i < 4; i++) s = fma((double)xv0[i], (double)w0[i], s);
#pragma unroll
            for (int i = 0; i < 4; i++) s = fma((double)xv1[i], (double)w1[i], s);
#pragma unroll
            for (int i = 0; i < 4; i++) s = fma((double)xv2[i], (double)w2[i], s);
#pragma unroll
            for (int i = 0; i < 4; i++) s = fma((double)xv3[i], (double)w3[i], s);
#pragma unroll
            for (int off = 32; off > 0; off >>= 1) s += __shfl_xor(s, off);
            s += (double)bn[ce];
            if (lane == 0) s_log[r * 65 + ce] = (float)s;
        }
    }
    __syncthreads();

    // re-select flagged rows with corrected logits
    if (lane < 16) {
        const int r = wid * 16 + lane;
        if (s_gap[r] < TAUF) {
            float g2, v2;
            out[blockRow + r] = do_row(r, g2, v2);
        }
    }
}

extern "C" void kernel_launch(void* const* d_in, const int* in_sizes, int n_in,
                              void* d_out, int out_size, void* d_ws, size_t ws_size,
                              hipStream_t stream)
{
    // setup_inputs order: x, Wg, bg, Wn, bn, We, noise  (Wg/bg/noise are dead code)
    const float* x  = (const float*)d_in[0];
    const float* Wn = (const float*)d_in[3];
    const float* bn = (const float*)d_in[4];
    const float* We = (const float*)d_in[5];
    float* out = (float*)d_out;

    const int B = in_sizes[0] / DDIM;           // 65536
    const int grid = B / ROWS;                  // 1024

    const size_t need = (size_t)NTILE * 12288;  // 384 KiB permuted W
    if (d_ws != nullptr && ws_size >= need) {
        conv_w_kernel<<<(NEXP * DDIM / 8) / 256, 256, 0, stream>>>(Wn, We, (char*)d_ws);
        moe_kernel<1><<<grid, 256, 0, stream>>>(x, Wn, bn, We, (const char*)d_ws, out);
    } else {
        moe_kernel<0><<<grid, 256, 0, stream>>>(x, Wn, bn, We, nullptr, out);
    }
}

// Round 4
// 126.869 us; speedup vs baseline: 1.0672x; 1.0672x over previous
//
#include <hip/hip_runtime.h>

#define DDIM 1024
#define NEXP 64
#define TOPK 8
#define BK 32
#define ROWS 64
#define NTILE 32
#define TAUF 5.0e-3f
#define TAUB 1.0e-2f

typedef __attribute__((ext_vector_type(8))) short short8;
typedef __attribute__((ext_vector_type(4))) float f32x4;

static __device__ __forceinline__ unsigned int f2u(float f) { return __builtin_bit_cast(unsigned int, f); }
static __device__ __forceinline__ float u2f(unsigned int u) { return __builtin_bit_cast(float, u); }

static __device__ __forceinline__ unsigned short bf_hi_rne(float x) {
    unsigned int u = f2u(x);
    return (unsigned short)((u + (0x7FFFu + ((u >> 16) & 1u))) >> 16);
}

static __device__ __forceinline__ void split2(float x, unsigned short& h, unsigned short& l) {
    unsigned int u = f2u(x);
    unsigned int uh = (u + (0x7FFFu + ((u >> 16) & 1u))) & 0xFFFF0000u;
    h = (unsigned short)(uh >> 16);
    float rem = x - u2f(uh);
    l = (unsigned short)(f2u(rem) >> 16);
}

// Prologue: pre-permute W into per-(tile,wave) register-load order.
// For tile t, wave q, array a (0=wn_hi,1=wn_lo,2=we_hi), lane l = c*16 + (e&15):
//   ws byte offset = t*12288 + q*3072 + a*1024 + l*16
// so the main kernel's wave reads 1KB contiguous per array (perfectly coalesced).
__global__ __launch_bounds__(256) void conv_w_kernel(
    const float* __restrict__ Wn, const float* __restrict__ We, char* __restrict__ wsW)
{
    int g = blockIdx.x * 256 + threadIdx.x;   // 0..8191
    int e = g >> 7, c128 = g & 127;
    int k = c128 << 3;                        // 8-float group start
    int t = k >> 5, c = (k >> 3) & 3;
    const float* np = Wn + (size_t)e * DDIM + k;
    const float* ep = We + (size_t)e * DDIM + k;
    f32x4 n0 = ((const f32x4*)np)[0], n1 = ((const f32x4*)np)[1];
    f32x4 e0 = ((const f32x4*)ep)[0], e1 = ((const f32x4*)ep)[1];
    short8 nh, nl, eh;
#pragma unroll
    for (int i = 0; i < 4; i++) { unsigned short h, l; split2(n0[i], h, l); nh[i] = (short)h; nl[i] = (short)l; }
#pragma unroll
    for (int i = 0; i < 4; i++) { unsigned short h, l; split2(n1[i], h, l); nh[i + 4] = (short)h; nl[i + 4] = (short)l; }
#pragma unroll
    for (int i = 0; i < 4; i++) eh[i] = (short)bf_hi_rne(e0[i]);
#pragma unroll
    for (int i = 0; i < 4; i++) eh[i + 4] = (short)bf_hi_rne(e1[i]);
    size_t dst = (size_t)t * 12288 + (size_t)(e >> 4) * 3072 + (size_t)((c * 16 + (e & 15)) * 16);
    *(short8*)(wsW + dst)        = nh;
    *(short8*)(wsW + dst + 1024) = nl;
    *(short8*)(wsW + dst + 2048) = eh;
}

// LDS: x double-buffer [2][64 rows][32 k] bf16 (8 KB, XOR-swizzled); epilogue overlays
// s_log[64][65] @0, s_exp @16640, s_gap @33280, s_vb @33536.  W lives in registers.
template <int PRE>
__global__ __launch_bounds__(256, 4) void moe_kernel(
    const float* __restrict__ x, const float* __restrict__ Wn,
    const float* __restrict__ bn, const float* __restrict__ We,
    const char* __restrict__ wsW, float* __restrict__ out)
{
    __shared__ __align__(16) char smem[33792];

    const int tid = threadIdx.x;
    const int wid = tid >> 6;
    const int lane = tid & 63;
    const int fr = lane & 15;
    const int fq = lane >> 4;
    const int blockRow = blockIdx.x * ROWS;

    // x staging role: thread covers row srow, 8-float chunk sg (coalesced 128B/row)
    const int srow = tid >> 2, sg = tid & 3;
    const int swz = (srow * 64 + sg * 16) ^ ((srow & 7) << 4);
    const float* xsrc = x + (size_t)(blockRow + srow) * DDIM + sg * 8;

    f32x4 sxA0, sxA1, sxB0, sxB1;         // x prefetch regs, two sets
    short8 whA, wlA, ehA, whB, wlB, ehB;  // W fragment regs, two sets

    const char* wbase = wsW + wid * 3072 + lane * 16;

#define XLOAD_A(t) { const float* p = xsrc + (t) * BK; sxA0 = ((const f32x4*)p)[0]; sxA1 = ((const f32x4*)p)[1]; }
#define XLOAD_B(t) { const float* p = xsrc + (t) * BK; sxB0 = ((const f32x4*)p)[0]; sxB1 = ((const f32x4*)p)[1]; }

#define WLOAD(t, wh, wl, eh) { \
    if constexpr (PRE) { \
        const char* wp = wbase + (size_t)(t) * 12288; \
        wh = *(const short8*)(wp); \
        wl = *(const short8*)(wp + 1024); \
        eh = *(const short8*)(wp + 2048); \
    } else { \
        const float* np = Wn + (size_t)(wid * 16 + fr) * DDIM + (t) * BK + fq * 8; \
        const float* ep = We + (size_t)(wid * 16 + fr) * DDIM + (t) * BK + fq * 8; \
        f32x4 n0 = ((const f32x4*)np)[0], n1 = ((const f32x4*)np)[1]; \
        f32x4 e0 = ((const f32x4*)ep)[0], e1 = ((const f32x4*)ep)[1]; \
        for (int i = 0; i < 4; i++) { unsigned short h, l; split2(n0[i], h, l); wh[i] = (short)h; wl[i] = (short)l; } \
        for (int i = 0; i < 4; i++) { unsigned short h, l; split2(n1[i], h, l); wh[i + 4] = (short)h; wl[i + 4] = (short)l; } \
        for (int i = 0; i < 4; i++) eh[i] = (short)bf_hi_rne(e0[i]); \
        for (int i = 0; i < 4; i++) eh[i + 4] = (short)bf_hi_rne(e1[i]); \
    } }

#define STAGE_WRITE(b, s0, s1) { \
    short8 xh; \
    for (int i = 0; i < 4; i++) xh[i] = (short)bf_hi_rne(s0[i]); \
    for (int i = 0; i < 4; i++) xh[i + 4] = (short)bf_hi_rne(s1[i]); \
    *(short8*)(smem + (b) * 4096 + swz) = xh; }

    f32x4 accN[4], accE[4];
#pragma unroll
    for (int rt = 0; rt < 4; rt++) { accN[rt] = f32x4{0.f,0.f,0.f,0.f}; accE[rt] = f32x4{0.f,0.f,0.f,0.f}; }

#define COMPUTE(b, wh, wl, eh) { \
    const char* xb = smem + (b) * 4096; \
    _Pragma("unroll") \
    for (int rt = 0; rt < 4; rt++) { \
        const int row = rt * 16 + fr; \
        const int xoff = (row * 64 + fq * 16) ^ ((row & 7) << 4); \
        short8 xh = *(const short8*)(xb + xoff); \
        accN[rt] = __builtin_amdgcn_mfma_f32_16x16x32_bf16(xh, wh, accN[rt], 0, 0, 0); \
        accN[rt] = __builtin_amdgcn_mfma_f32_16x16x32_bf16(xh, wl, accN[rt], 0, 0, 0); \
        accE[rt] = __builtin_amdgcn_mfma_f32_16x16x32_bf16(xh, eh, accE[rt], 0, 0, 0); \
    } }

#define BAR() { asm volatile("s_waitcnt lgkmcnt(0)" ::: "memory"); \
                __builtin_amdgcn_s_barrier(); \
                asm volatile("" ::: "memory"); }

    // ---- prologue: x tiles 0,1,2 in flight; W tiles 0,1 in flight
    XLOAD_A(0); WLOAD(0, whA, wlA, ehA);
    XLOAD_B(1); WLOAD(1, whB, wlB, ehB);
    STAGE_WRITE(0, sxA0, sxA1);           // consumes sxA (tile 0)
    XLOAD_A(2);                           // sxA = tile 2
    BAR();

    // ---- main loop: tiles in pairs; compute FIRST, then refills; vmcnt never drained
    for (int p = 0; p < NTILE / 2; ++p) {
        const int t0 = 2 * p, t1 = 2 * p + 1;
        // tile t0: regs A, lds buf 0
        COMPUTE(0, whA, wlA, ehA);
        STAGE_WRITE(1, sxB0, sxB1);                    // write tile t0+1 (buf1)
        if (t0 + 3 < NTILE) XLOAD_B(t0 + 3);           // sxB = tile t0+3
        if (t0 + 2 < NTILE) WLOAD(t0 + 2, whA, wlA, ehA);
        BAR();
        // tile t1: regs B, lds buf 1
        COMPUTE(1, whB, wlB, ehB);
        if (t1 + 1 < NTILE) {
            STAGE_WRITE(0, sxA0, sxA1);                // write tile t1+1 (buf0)
            if (t1 + 3 < NTILE) XLOAD_A(t1 + 3);
            WLOAD(t1 + 2, whB, wlB, ehB);
            BAR();
        }
    }
    __syncthreads();

    // ---- epilogue overlay
    float* s_log = (float*)smem;                 // [64][65]
    float* s_exp = (float*)(smem + 16640);       // [64][65]
    float* s_gap = (float*)(smem + 33280);       // [64]
    float* s_vb  = (float*)(smem + 33536);       // [64]

    const int ecol = wid * 16 + fr;
    const float be = bn[ecol];
#pragma unroll
    for (int rt = 0; rt < 4; rt++) {
#pragma unroll
        for (int j = 0; j < 4; j++) {
            const int r = rt * 16 + fq * 4 + j;  // C/D: col=lane&15, row=(lane>>4)*4+j
            s_log[r * 65 + ecol] = accN[rt][j] + be;
            s_exp[r * 65 + ecol] = accE[rt][j];
        }
    }
    __syncthreads();

    auto do_row = [&](int r, float& gapo, float& vbo) -> float {
        float selv[TOPK]; int seli[TOPK];
        unsigned long long chosen = 0ull;
#pragma unroll
        for (int t = 0; t < TOPK; t++) {
            float best = -3.0e38f; int bi = 0;
#pragma unroll 4
            for (int e = 0; e < NEXP; e++) {
                float v = s_log[r * 65 + e];
                if (!((chosen >> e) & 1ull) && v > best) { best = v; bi = e; }  // strict > => lowest idx wins ties
            }
            selv[t] = best; seli[t] = bi; chosen |= (1ull << bi);
        }
        float v9 = -3.0e38f;
#pragma unroll 4
        for (int e = 0; e < NEXP; e++) {
            float v = s_log[r * 65 + e];
            if (!((chosen >> e) & 1ull) && v > v9) v9 = v;
        }
        gapo = selv[TOPK - 1] - v9;
        vbo = 0.5f * (selv[TOPK - 1] + v9);
        float m = selv[0], Z = 0.f, o = 0.f;
#pragma unroll
        for (int t = 0; t < TOPK; t++) {
            float w = __expf(selv[t] - m);
            Z += w;
            o += w * s_exp[r * 65 + seli[t]];
        }
        return o / Z;
    };

    // selection: wave w owns rows [w*16, w*16+16), one row per lane (lanes 0-15)
    if (lane < 16) {
        const int r = wid * 16 + lane;
        float gap, vb;
        float res = do_row(r, gap, vb);
        out[blockRow + r] = res;
        s_gap[r] = gap; s_vb[r] = vb;
    }
    __syncthreads();

    // fp64 fixup for near-tie rows, distributed: wave w handles rows r%4==w
    for (int r = wid; r < ROWS; r += 4) {
        if (!(s_gap[r] < TAUF)) continue;
        const float vbr = s_vb[r];
        const float ve = s_log[r * 65 + lane];
        unsigned long long cand = __ballot(fabsf(ve - vbr) <= TAUB);
        const f32x4* xq = (const f32x4*)(x + (size_t)(blockRow + r) * DDIM) + lane * 4;
        const f32x4 xv0 = xq[0], xv1 = xq[1], xv2 = xq[2], xv3 = xq[3];
        while (cand) {
            const int ce = __builtin_ctzll(cand);
            cand &= cand - 1;
            const f32x4* wq = (const f32x4*)(Wn + (size_t)ce * DDIM) + lane * 4;
            const f32x4 w0 = wq[0], w1 = wq[1], w2 = wq[2], w3 = wq[3];
            double s = 0.0;
#pragma unroll
            for (int i = 0; i < 4; i++) s = fma((double)xv0[i], (double)w0[i], s);
#pragma unroll
            for (int i = 0; i < 4; i++) s = fma((double)xv1[i], (double)w1[i], s);
#pragma unroll
            for (int i = 0; i < 4; i++) s = fma((double)xv2[i], (double)w2[i], s);
#pragma unroll
            for (int i = 0; i < 4; i++) s = fma((double)xv3[i], (double)w3[i], s);
#pragma unroll
            for (int off = 32; off > 0; off >>= 1) s += __shfl_xor(s, off);
            s += (double)bn[ce];
            if (lane == 0) s_log[r * 65 + ce] = (float)s;
        }
    }
    __syncthreads();

    // re-select flagged rows with corrected logits
    if (lane < 16) {
        const int r = wid * 16 + lane;
        if (s_gap[r] < TAUF) {
            float g2, v2;
            out[blockRow + r] = do_row(r, g2, v2);
        }
    }
}

extern "C" void kernel_launch(void* const* d_in, const int* in_sizes, int n_in,
                              void* d_out, int out_size, void* d_ws, size_t ws_size,
                              hipStream_t stream)
{
    // setup_inputs order: x, Wg, bg, Wn, bn, We, noise  (Wg/bg/noise are dead code)
    const float* x  = (const float*)d_in[0];
    const float* Wn = (const float*)d_in[3];
    const float* bn = (const float*)d_in[4];
    const float* We = (const float*)d_in[5];
    float* out = (float*)d_out;

    const int B = in_sizes[0] / DDIM;           // 65536
    const int grid = B / ROWS;                  // 1024

    const size_t need = (size_t)NTILE * 12288;  // 384 KiB permuted W
    if (d_ws != nullptr && ws_size >= need) {
        conv_w_kernel<<<(NEXP * DDIM / 8) / 256, 256, 0, stream>>>(Wn, We, (char*)d_ws);
        moe_kernel<1><<<grid, 256, 0, stream>>>(x, Wn, bn, We, (const char*)d_ws, out);
    } else {
        moe_kernel<0><<<grid, 256, 0, stream>>>(x, Wn, bn, We, nullptr, out);
    }
}